// Round 21
// baseline (35.468 us; speedup 1.0000x reference)
//
#include <hip/hip_runtime.h>

// MLP 30->24->19->14->10->6->2->1 via MFMA (v_mfma_f32_32x32x16_f16).
// R21 vs R20 (35.1us): BARRIER-FREE wave-private staging.
//  - Each wave stages its OWN 32-row x tile (3840B) into a private LDS
//    segment: 4 coalesced dwordx4/lane -> ds_write_b128 -> in-wave lgkmcnt
//    ordering. NO __syncthreads in the tile loop (R20 barrier-coupled all
//    4 waves to the slowest stager every slab).
//  - Wave pipeline per tile: ds_write(t) -> frag-read(t) -> issue global
//    loads(t+1) -> 10-MFMA chain(t) -> store(t). Loads hide under MFMA.
//  - 4 tiles/wave (128 consecutive rows), grid 2048; weights staged once
//    per block + one barrier; all 10 A-frags hoisted to registers (R20 win).
// Layouts (numerically verified R19/R20, absmax 1.95e-3):
//  C/D: col=lane&31, row=(reg&3)+8*(reg>>2)+4*(lane>>5).
//  A/B: lane holds elem[m_or_n=lane&31][k=16*ks+8*(lane>>5)+j].
//  Bias folded as extra K-slot (W_eff[m][FIN]=bias, act k=FIN = 1.0).

#define NTHREADS 256
#define TPW 4                  // tiles (32 rows) per wave

typedef __fp16       h2     __attribute__((ext_vector_type(2)));
typedef __fp16       half8  __attribute__((ext_vector_type(8)));
typedef float        f32x16 __attribute__((ext_vector_type(16)));
typedef unsigned int uint4v __attribute__((ext_vector_type(4)));

__device__ __forceinline__ h2 cpk(float a, float b) {
    return __builtin_bit_cast(h2, __builtin_amdgcn_cvt_pkrtz(a, b));
}
__device__ __forceinline__ h2 relu2(h2 v) {
    h2 z = {(__fp16)0.f, (__fp16)0.f};
#if __has_builtin(__builtin_elementwise_max)
    return __builtin_elementwise_max(v, z);
#else
    v.x = v.x > (__fp16)0.f ? v.x : (__fp16)0.f;
    v.y = v.y > (__fp16)0.f ? v.y : (__fp16)0.f;
    return v;
#endif
}
__device__ __forceinline__ unsigned ucast(h2 v) { return __builtin_bit_cast(unsigned, v); }

__device__ __forceinline__ f32x16 mfma_(half8 A, half8 B, f32x16 C) {
    return __builtin_amdgcn_mfma_f32_32x32x16_f16(A, B, C, 0, 0, 0);
}

// ---- weight staging: W_eff[m][k] f16, m padded to 32, k padded to KPAD ----
template <int FIN, int FOUT, int KPAD>
__device__ __forceinline__ void stageW(const float* __restrict__ W, const float* __restrict__ B,
                                       __fp16* __restrict__ sbase, int t) {
    for (int idx = t; idx < 32 * KPAD; idx += NTHREADS) {
        int m = idx / KPAD;
        int k = idx & (KPAD - 1);
        float v = 0.f;
        if (m < FOUT) {
            if (k < FIN) v = W[m * FIN + k];
            else if (k == FIN) v = B[m];
        }
        int byte = idx * 2;
        byte ^= (m & 7) << 4;
        *(__fp16*)((char*)sbase + byte) = (__fp16)v;
    }
}

// A-fragment read: lane holds W_eff[m=lane&31][k = ks*16 + 8*(lane>>5) + j]
__device__ __forceinline__ half8 ldA(const __fp16* base, int KPAD, int ks, int lane) {
    int m = lane & 31;
    int byte = (m * KPAD + ks * 16 + ((lane >> 5) & 1) * 8) * 2;
    byte ^= (m & 7) << 4;
    return __builtin_bit_cast(half8, *(const uint4v*)((const char*)base + byte));
}

// B-fragment from accumulator D, k-block regs R (0 or 8); POS = bias slot.
template <int R, int POS>
__device__ __forceinline__ half8 bfrag(const f32x16& d, int lane) {
    unsigned u0 = ucast(relu2(cpk(d[R + 0], d[R + 1])));
    unsigned u1 = ucast(relu2(cpk(d[R + 2], d[R + 3])));
    unsigned u2 = ucast(relu2(cpk(d[R + 4], d[R + 5])));
    unsigned u3 = ucast(relu2(cpk(d[R + 6], d[R + 7])));
    bool lo = (lane & 32) == 0;
    unsigned s0 = __shfl_xor(u0, 32), s1 = __shfl_xor(u1, 32);
    unsigned s2 = __shfl_xor(u2, 32), s3 = __shfl_xor(u3, 32);
    unsigned w0 = lo ? u0 : s2;
    unsigned w1 = lo ? u1 : s3;
    unsigned w2 = lo ? s0 : u2;
    unsigned w3 = lo ? s1 : u3;
    if constexpr (POS >= 0) {
        constexpr bool hiT = POS >= 8;
        constexpr int  p   = POS & 7;
        constexpr unsigned bits = (p & 1) ? 0x3C000000u : 0x00003C00u;  // f16 1.0
        bool sel = (((lane & 32) != 0) == hiT);
        unsigned ob = sel ? bits : 0u;
        if constexpr ((p >> 1) == 0) w0 |= ob;
        else if constexpr ((p >> 1) == 1) w1 |= ob;
        else if constexpr ((p >> 1) == 2) w2 |= ob;
        else w3 |= ob;
    }
    uint4v u = {w0, w1, w2, w3};
    return __builtin_bit_cast(half8, u);
}

__device__ __forceinline__ half8 packx(unsigned a, unsigned b, unsigned c, unsigned d) {
    uint4v u = {a, b, c, d};
    return __builtin_bit_cast(half8, u);
}

__global__ __launch_bounds__(NTHREADS, 3) void mlp_mfma3(
    const float* __restrict__ x,
    const float* __restrict__ W1, const float* __restrict__ B1,
    const float* __restrict__ W2, const float* __restrict__ B2,
    const float* __restrict__ W3, const float* __restrict__ B3,
    const float* __restrict__ W4, const float* __restrict__ B4,
    const float* __restrict__ W5, const float* __restrict__ B5,
    const float* __restrict__ W6, const float* __restrict__ B6,
    const float* __restrict__ W7, const float* __restrict__ B7,
    float* __restrict__ out, int nrows)
{
    __shared__ __align__(16) __fp16 shw[5120];        // weights, 10.2 KB
    __shared__ __align__(16) float  sxw[4][960];      // per-wave 32-row tile, 15.4 KB

    const int t    = threadIdx.x;
    const int lane = t & 63;
    const int wid  = t >> 6;
    const int hb   = (lane >> 5) & 1;

    stageW<30, 24, 32>(W1, B1, shw + 0,    t);
    stageW<24, 19, 32>(W2, B2, shw + 1024, t);
    stageW<19, 14, 32>(W3, B3, shw + 2048, t);
    stageW<14, 10, 16>(W4, B4, shw + 3072, t);
    stageW<10, 6,  16>(W5, B5, shw + 3584, t);
    stageW<6,  2,  16>(W6, B6, shw + 4096, t);
    stageW<2,  1,  16>(W7, B7, shw + 4608, t);
    __syncthreads();                                  // the ONLY barrier

    // ---- hoist all A-fragments into registers (10 x 4 VGPR) ----
    const half8 A10 = ldA(shw + 0,    32, 0, lane), A11 = ldA(shw + 0,    32, 1, lane);
    const half8 A20 = ldA(shw + 1024, 32, 0, lane), A21 = ldA(shw + 1024, 32, 1, lane);
    const half8 A30 = ldA(shw + 2048, 32, 0, lane), A31 = ldA(shw + 2048, 32, 1, lane);
    const half8 A4  = ldA(shw + 3072, 16, 0, lane);
    const half8 A5  = ldA(shw + 3584, 16, 0, lane);
    const half8 A6  = ldA(shw + 4096, 16, 0, lane);
    const half8 A7  = ldA(shw + 4608, 16, 0, lane);

    const f32x16 z = {0.f,0.f,0.f,0.f, 0.f,0.f,0.f,0.f, 0.f,0.f,0.f,0.f, 0.f,0.f,0.f,0.f};

    const int tile0 = (blockIdx.x * 4 + wid) * TPW;   // 4 consecutive tiles/wave
    float4* wb = (float4*)sxw[wid];

    // prefetch tile 0 (coalesced: lane l -> float4 l, l+64, l+128, l+192)
    float4 pf0, pf1, pf2, pf3;
    {
        const float4* gx = (const float4*)x + (size_t)tile0 * 240;
        pf0 = gx[lane];
        pf1 = gx[lane + 64];
        pf2 = gx[lane + 128];
        if (lane < 48) pf3 = gx[lane + 192];
    }

    for (int it = 0; it < TPW; ++it) {
        const int T = tile0 + it;

        // ---- stage current tile into wave-private LDS (no barrier) ----
        wb[lane]       = pf0;
        wb[lane + 64]  = pf1;
        wb[lane + 128] = pf2;
        if (lane < 48) wb[lane + 192] = pf3;

        // ---- read B-fragments for layer 1 (in-wave lgkmcnt ordering) ----
        const float* xr = sxw[wid] + (lane & 31) * 30;
        float f0a[8], f1a[8];
        {
            const float2* p0 = (const float2*)(xr + hb * 8);
            float2 a = p0[0], b = p0[1], c = p0[2], d = p0[3];
            f0a[0] = a.x; f0a[1] = a.y; f0a[2] = b.x; f0a[3] = b.y;
            f0a[4] = c.x; f0a[5] = c.y; f0a[6] = d.x; f0a[7] = d.y;
            const float2* p1 = (const float2*)(xr + 16 + hb * 8);
            float2 e = p1[0], g = p1[1], h = p1[2], i = p1[3];
            f1a[0] = e.x; f1a[1] = e.y; f1a[2] = g.x; f1a[3] = g.y;
            f1a[4] = h.x; f1a[5] = h.y; f1a[6] = i.x; f1a[7] = i.y;
        }
        half8 Bx0 = packx(ucast(cpk(f0a[0], f0a[1])), ucast(cpk(f0a[2], f0a[3])),
                          ucast(cpk(f0a[4], f0a[5])), ucast(cpk(f0a[6], f0a[7])));
        unsigned x13 = hb ? 0x00003C00u : ucast(cpk(f1a[6], f1a[7]));  // bias 1.0 @ k=30
        half8 Bx1 = packx(ucast(cpk(f1a[0], f1a[1])), ucast(cpk(f1a[2], f1a[3])),
                          ucast(cpk(f1a[4], f1a[5])), x13);

        // ---- issue next tile's global loads (hide under MFMA chain) ----
        if (it + 1 < TPW) {
            const float4* gx = (const float4*)x + (size_t)(T + 1) * 240;
            pf0 = gx[lane];
            pf1 = gx[lane + 64];
            pf2 = gx[lane + 128];
            if (lane < 48) pf3 = gx[lane + 192];
        }

        // ---- 10-MFMA chain ----
        f32x16 a1 = mfma_(A10, Bx0, z);
        a1 = mfma_(A11, Bx1, a1);
        f32x16 a2 = mfma_(A20, bfrag<0, -1>(a1, lane), z);
        a2 = mfma_(A21, bfrag<8, 8>(a1, lane), a2);
        f32x16 a3 = mfma_(A30, bfrag<0, -1>(a2, lane), z);
        a3 = mfma_(A31, bfrag<8, 3>(a2, lane), a3);
        f32x16 a4 = mfma_(A4, bfrag<0, 14>(a3, lane), z);
        f32x16 a5 = mfma_(A5, bfrag<0, 10>(a4, lane), z);
        f32x16 a6 = mfma_(A6, bfrag<0, 6>(a5, lane), z);
        f32x16 a7 = mfma_(A7, bfrag<0, 2>(a6, lane), z);

        const int row0 = T * 32;
        if (lane < 32) {
            int r = row0 + lane;
            if (r < nrows) out[r] = a7[0];
        }
    }
}

extern "C" void kernel_launch(void* const* d_in, const int* in_sizes, int n_in,
                              void* d_out, int out_size, void* d_ws, size_t ws_size,
                              hipStream_t stream) {
    const float* x = (const float*)d_in[0];
    int nrows = in_sizes[0] / 30;
    int rows_per_block = 4 * TPW * 32;                // 512
    int blocks = (nrows + rows_per_block - 1) / rows_per_block;
    mlp_mfma3<<<blocks, NTHREADS, 0, stream>>>(
        x,
        (const float*)d_in[1],  (const float*)d_in[2],
        (const float*)d_in[3],  (const float*)d_in[4],
        (const float*)d_in[5],  (const float*)d_in[6],
        (const float*)d_in[7],  (const float*)d_in[8],
        (const float*)d_in[9],  (const float*)d_in[10],
        (const float*)d_in[11], (const float*)d_in[12],
        (const float*)d_in[13], (const float*)d_in[14],
        (float*)d_out, nrows);
}

// Round 22
// 31.319 us; speedup vs baseline: 1.1325x; 1.1325x over previous
//
#include <hip/hip_runtime.h>

// MLP 30->24->19->14->10->6->2->1 via MFMA (v_mfma_f32_32x32x16_f16).
// R22 vs R21 (35.5us, latency-bound on per-tile serial chain):
//  - NO x LDS staging: each lane loads ITS OWN B-frag slice directly from
//    global (row = lane&31, k-offset 8*hb) as float2s, converted straight
//    to f16 frag words. Removes ds_write + lgkm + stride-120 conflict reads
//    from the serial chain (R21: 1.3M bank conflicts).
//  - Prefetch next tile's 8 float2 during current MFMA chain (T14).
//  - LDS 25.6 -> 10.2 KB (weights only); __launch_bounds__(256,4), TPW=8,
//    grid 1024 -> ONE full-residency generation at 16 waves/CU.
// Layouts (numerically verified R19-R21, absmax 1.95e-3):
//  C/D: col=lane&31, row=(reg&3)+8*(reg>>2)+4*(lane>>5).
//  A/B: lane holds elem[m_or_n=lane&31][k=16*ks+8*(lane>>5)+j].
//  Bias folded as extra K-slot (W_eff[m][FIN]=bias, act k=FIN = 1.0).

#define NTHREADS 256
#define TPW 8                  // tiles (32 rows) per wave

typedef __fp16       h2     __attribute__((ext_vector_type(2)));
typedef __fp16       half8  __attribute__((ext_vector_type(8)));
typedef float        f32x16 __attribute__((ext_vector_type(16)));
typedef unsigned int uint4v __attribute__((ext_vector_type(4)));

__device__ __forceinline__ h2 cpk(float a, float b) {
    return __builtin_bit_cast(h2, __builtin_amdgcn_cvt_pkrtz(a, b));
}
__device__ __forceinline__ h2 relu2(h2 v) {
    h2 z = {(__fp16)0.f, (__fp16)0.f};
#if __has_builtin(__builtin_elementwise_max)
    return __builtin_elementwise_max(v, z);
#else
    v.x = v.x > (__fp16)0.f ? v.x : (__fp16)0.f;
    v.y = v.y > (__fp16)0.f ? v.y : (__fp16)0.f;
    return v;
#endif
}
__device__ __forceinline__ unsigned ucast(h2 v) { return __builtin_bit_cast(unsigned, v); }

__device__ __forceinline__ f32x16 mfma_(half8 A, half8 B, f32x16 C) {
    return __builtin_amdgcn_mfma_f32_32x32x16_f16(A, B, C, 0, 0, 0);
}

// ---- weight staging: W_eff[m][k] f16, m padded to 32, k padded to KPAD ----
template <int FIN, int FOUT, int KPAD>
__device__ __forceinline__ void stageW(const float* __restrict__ W, const float* __restrict__ B,
                                       __fp16* __restrict__ sbase, int t) {
    for (int idx = t; idx < 32 * KPAD; idx += NTHREADS) {
        int m = idx / KPAD;
        int k = idx & (KPAD - 1);
        float v = 0.f;
        if (m < FOUT) {
            if (k < FIN) v = W[m * FIN + k];
            else if (k == FIN) v = B[m];
        }
        int byte = idx * 2;
        byte ^= (m & 7) << 4;
        *(__fp16*)((char*)sbase + byte) = (__fp16)v;
    }
}

// A-fragment read: lane holds W_eff[m=lane&31][k = ks*16 + 8*(lane>>5) + j]
__device__ __forceinline__ half8 ldA(const __fp16* base, int KPAD, int ks, int lane) {
    int m = lane & 31;
    int byte = (m * KPAD + ks * 16 + ((lane >> 5) & 1) * 8) * 2;
    byte ^= (m & 7) << 4;
    return __builtin_bit_cast(half8, *(const uint4v*)((const char*)base + byte));
}

// B-fragment from accumulator D, k-block regs R (0 or 8); POS = bias slot.
template <int R, int POS>
__device__ __forceinline__ half8 bfrag(const f32x16& d, int lane) {
    unsigned u0 = ucast(relu2(cpk(d[R + 0], d[R + 1])));
    unsigned u1 = ucast(relu2(cpk(d[R + 2], d[R + 3])));
    unsigned u2 = ucast(relu2(cpk(d[R + 4], d[R + 5])));
    unsigned u3 = ucast(relu2(cpk(d[R + 6], d[R + 7])));
    bool lo = (lane & 32) == 0;
    unsigned s0 = __shfl_xor(u0, 32), s1 = __shfl_xor(u1, 32);
    unsigned s2 = __shfl_xor(u2, 32), s3 = __shfl_xor(u3, 32);
    unsigned w0 = lo ? u0 : s2;
    unsigned w1 = lo ? u1 : s3;
    unsigned w2 = lo ? s0 : u2;
    unsigned w3 = lo ? s1 : u3;
    if constexpr (POS >= 0) {
        constexpr bool hiT = POS >= 8;
        constexpr int  p   = POS & 7;
        constexpr unsigned bits = (p & 1) ? 0x3C000000u : 0x00003C00u;  // f16 1.0
        bool sel = (((lane & 32) != 0) == hiT);
        unsigned ob = sel ? bits : 0u;
        if constexpr ((p >> 1) == 0) w0 |= ob;
        else if constexpr ((p >> 1) == 1) w1 |= ob;
        else if constexpr ((p >> 1) == 2) w2 |= ob;
        else w3 |= ob;
    }
    uint4v u = {w0, w1, w2, w3};
    return __builtin_bit_cast(half8, u);
}

__device__ __forceinline__ half8 packx(unsigned a, unsigned b, unsigned c, unsigned d) {
    uint4v u = {a, b, c, d};
    return __builtin_bit_cast(half8, u);
}

__global__ __launch_bounds__(NTHREADS, 4) void mlp_mfma4(
    const float* __restrict__ x,
    const float* __restrict__ W1, const float* __restrict__ B1,
    const float* __restrict__ W2, const float* __restrict__ B2,
    const float* __restrict__ W3, const float* __restrict__ B3,
    const float* __restrict__ W4, const float* __restrict__ B4,
    const float* __restrict__ W5, const float* __restrict__ B5,
    const float* __restrict__ W6, const float* __restrict__ B6,
    const float* __restrict__ W7, const float* __restrict__ B7,
    float* __restrict__ out, int nrows)
{
    __shared__ __align__(16) __fp16 shw[5120];        // weights only, 10.2 KB

    const int t    = threadIdx.x;
    const int lane = t & 63;
    const int wid  = t >> 6;
    const int hb   = (lane >> 5) & 1;

    stageW<30, 24, 32>(W1, B1, shw + 0,    t);
    stageW<24, 19, 32>(W2, B2, shw + 1024, t);
    stageW<19, 14, 32>(W3, B3, shw + 2048, t);
    stageW<14, 10, 16>(W4, B4, shw + 3072, t);
    stageW<10, 6,  16>(W5, B5, shw + 3584, t);
    stageW<6,  2,  16>(W6, B6, shw + 4096, t);
    stageW<2,  1,  16>(W7, B7, shw + 4608, t);
    __syncthreads();                                  // the ONLY barrier

    // ---- hoist all A-fragments into registers (10 x 4 VGPR) ----
    const half8 A10 = ldA(shw + 0,    32, 0, lane), A11 = ldA(shw + 0,    32, 1, lane);
    const half8 A20 = ldA(shw + 1024, 32, 0, lane), A21 = ldA(shw + 1024, 32, 1, lane);
    const half8 A30 = ldA(shw + 2048, 32, 0, lane), A31 = ldA(shw + 2048, 32, 1, lane);
    const half8 A4  = ldA(shw + 3072, 16, 0, lane);
    const half8 A5  = ldA(shw + 3584, 16, 0, lane);
    const half8 A6  = ldA(shw + 4096, 16, 0, lane);
    const half8 A7  = ldA(shw + 4608, 16, 0, lane);

    const f32x16 z = {0.f,0.f,0.f,0.f, 0.f,0.f,0.f,0.f, 0.f,0.f,0.f,0.f, 0.f,0.f,0.f,0.f};

    const int tile0 = (blockIdx.x * 4 + wid) * TPW;   // TPW consecutive tiles/wave
    const int myrow = lane & 31;

    // per-lane source: row (tile*32 + myrow), k-slice 8*hb (block0) and 16+8*hb (block1)
    // pf0..3 = block0 slice (k = 8*hb + 0..7); pf4..pf6(+pf7 lo-only) = block1 slice
    float2 pf0, pf1, pf2, pf3, pf4, pf5, pf6, pf7;
    {
        const float* b0 = x + ((size_t)(tile0 * 32 + myrow)) * 30 + hb * 8;
        pf0 = *(const float2*)(b0 + 0);
        pf1 = *(const float2*)(b0 + 2);
        pf2 = *(const float2*)(b0 + 4);
        pf3 = *(const float2*)(b0 + 6);
        const float* b1 = b0 + 16;
        pf4 = *(const float2*)(b1 + 0);
        pf5 = *(const float2*)(b1 + 2);
        pf6 = *(const float2*)(b1 + 4);
        if (!hb) pf7 = *(const float2*)(b1 + 6);      // hi lanes: k30,31 = bias slot
    }

    for (int it = 0; it < TPW; ++it) {
        const int T = tile0 + it;

        // ---- build layer-1 B-fragments straight from prefetch regs ----
        half8 Bx0 = packx(ucast(cpk(pf0.x, pf0.y)), ucast(cpk(pf1.x, pf1.y)),
                          ucast(cpk(pf2.x, pf2.y)), ucast(cpk(pf3.x, pf3.y)));
        unsigned xlast = hb ? 0x00003C00u : ucast(cpk(pf7.x, pf7.y));  // 1.0 @ k30
        half8 Bx1 = packx(ucast(cpk(pf4.x, pf4.y)), ucast(cpk(pf5.x, pf5.y)),
                          ucast(cpk(pf6.x, pf6.y)), xlast);

        // ---- issue next tile's loads (hide under MFMA chain) ----
        if (it + 1 < TPW) {
            const float* b0 = x + ((size_t)((T + 1) * 32 + myrow)) * 30 + hb * 8;
            pf0 = *(const float2*)(b0 + 0);
            pf1 = *(const float2*)(b0 + 2);
            pf2 = *(const float2*)(b0 + 4);
            pf3 = *(const float2*)(b0 + 6);
            const float* b1 = b0 + 16;
            pf4 = *(const float2*)(b1 + 0);
            pf5 = *(const float2*)(b1 + 2);
            pf6 = *(const float2*)(b1 + 4);
            if (!hb) pf7 = *(const float2*)(b1 + 6);
        }

        // ---- 10-MFMA chain ----
        f32x16 a1 = mfma_(A10, Bx0, z);
        a1 = mfma_(A11, Bx1, a1);
        f32x16 a2 = mfma_(A20, bfrag<0, -1>(a1, lane), z);
        a2 = mfma_(A21, bfrag<8, 8>(a1, lane), a2);
        f32x16 a3 = mfma_(A30, bfrag<0, -1>(a2, lane), z);
        a3 = mfma_(A31, bfrag<8, 3>(a2, lane), a3);
        f32x16 a4 = mfma_(A4, bfrag<0, 14>(a3, lane), z);
        f32x16 a5 = mfma_(A5, bfrag<0, 10>(a4, lane), z);
        f32x16 a6 = mfma_(A6, bfrag<0, 6>(a5, lane), z);
        f32x16 a7 = mfma_(A7, bfrag<0, 2>(a6, lane), z);

        const int row0 = T * 32;
        if (lane < 32) {
            int r = row0 + lane;
            if (r < nrows) out[r] = a7[0];
        }
    }
}

extern "C" void kernel_launch(void* const* d_in, const int* in_sizes, int n_in,
                              void* d_out, int out_size, void* d_ws, size_t ws_size,
                              hipStream_t stream) {
    const float* x = (const float*)d_in[0];
    int nrows = in_sizes[0] / 30;
    int rows_per_block = 4 * TPW * 32;                // 1024
    int blocks = (nrows + rows_per_block - 1) / rows_per_block;
    mlp_mfma4<<<blocks, NTHREADS, 0, stream>>>(
        x,
        (const float*)d_in[1],  (const float*)d_in[2],
        (const float*)d_in[3],  (const float*)d_in[4],
        (const float*)d_in[5],  (const float*)d_in[6],
        (const float*)d_in[7],  (const float*)d_in[8],
        (const float*)d_in[9],  (const float*)d_in[10],
        (const float*)d_in[11], (const float*)d_in[12],
        (const float*)d_in[13], (const float*)d_in[14],
        (float*)d_out, nrows);
}